// Round 1
// baseline (408.195 us; speedup 1.0000x reference)
//
#include <hip/hip_runtime.h>

// Problem constants (from reference): B=2, D=H=W=160, C=3, fp32.
constexpr int Bn = 2;
constexpr int Dn = 160;
constexpr int Hn = 160;
constexpr int Wn = 160;
constexpr int NV = Bn * Dn * Hn * Wn;          // 8,192,000 voxels
constexpr int VOL = Dn * Hn * Wn;              // 4,096,000 voxels / batch

__global__ __launch_bounds__(256) void compose_transform_kernel(
    const float* __restrict__ warp1,
    const float* __restrict__ warp2,
    float* __restrict__ out) {
    int idx = blockIdx.x * blockDim.x + threadIdx.x;   // voxel id over B*D*H*W
    if (idx >= NV) return;

    // decode (b, d, h, w) — compiler turns /160 into magic-mul
    int w  = idx % Wn;
    int t  = idx / Wn;
    int h  = t % Hn;
    t      = t / Hn;
    int d  = t % Dn;
    int b  = t / Dn;

    int base3 = idx * 3;
    float u2x = warp2[base3 + 0];
    float u2y = warp2[base3 + 1];
    float u2z = warp2[base3 + 2];

    // loc = grid + u2, clipped to [0, size-1]
    float lx = fminf(fmaxf((float)d + u2x, 0.0f), (float)(Dn - 1));
    float ly = fminf(fmaxf((float)h + u2y, 0.0f), (float)(Hn - 1));
    float lz = fminf(fmaxf((float)w + u2z, 0.0f), (float)(Wn - 1));

    float fx0 = floorf(lx);
    float fy0 = floorf(ly);
    float fz0 = floorf(lz);

    float wx1 = lx - fx0, wx0 = 1.0f - wx1;
    float wy1 = ly - fy0, wy0 = 1.0f - wy1;
    float wz1 = lz - fz0, wz0 = 1.0f - wz1;

    int ix0 = (int)fx0;
    int iy0 = (int)fy0;
    int iz0 = (int)fz0;
    int ix1 = min(ix0 + 1, Dn - 1);
    int iy1 = min(iy0 + 1, Hn - 1);
    int iz1 = min(iz0 + 1, Wn - 1);

    const float* __restrict__ u1 = warp1 + b * (VOL * 3);

    // Row bases for the 4 (x,y) corners; z handled inside.
    int r00 = (ix0 * Hn + iy0) * Wn;
    int r01 = (ix0 * Hn + iy1) * Wn;
    int r10 = (ix1 * Hn + iy0) * Wn;
    int r11 = (ix1 * Hn + iy1) * Wn;

    float accx = 0.0f, accy = 0.0f, accz = 0.0f;

    #define CORNER(rbase, iz, wgt)                         \
    {                                                      \
        int o = ((rbase) + (iz)) * 3;                      \
        float wv = (wgt);                                  \
        accx = fmaf(u1[o + 0], wv, accx);                  \
        accy = fmaf(u1[o + 1], wv, accy);                  \
        accz = fmaf(u1[o + 2], wv, accz);                  \
    }

    float wxy00 = wx0 * wy0;
    float wxy01 = wx0 * wy1;
    float wxy10 = wx1 * wy0;
    float wxy11 = wx1 * wy1;

    CORNER(r00, iz0, wxy00 * wz0);
    CORNER(r00, iz1, wxy00 * wz1);
    CORNER(r01, iz0, wxy01 * wz0);
    CORNER(r01, iz1, wxy01 * wz1);
    CORNER(r10, iz0, wxy10 * wz0);
    CORNER(r10, iz1, wxy10 * wz1);
    CORNER(r11, iz0, wxy11 * wz0);
    CORNER(r11, iz1, wxy11 * wz1);

    #undef CORNER

    out[base3 + 0] = u2x + accx;
    out[base3 + 1] = u2y + accy;
    out[base3 + 2] = u2z + accz;
}

extern "C" void kernel_launch(void* const* d_in, const int* in_sizes, int n_in,
                              void* d_out, int out_size, void* d_ws, size_t ws_size,
                              hipStream_t stream) {
    const float* warp1 = (const float*)d_in[0];
    const float* warp2 = (const float*)d_in[1];
    float* out = (float*)d_out;

    int threads = 256;
    int blocks = (NV + threads - 1) / threads;   // 32000 blocks
    compose_transform_kernel<<<blocks, threads, 0, stream>>>(warp1, warp2, out);
}

// Round 2
// 344.492 us; speedup vs baseline: 1.1849x; 1.1849x over previous
//
#include <hip/hip_runtime.h>

// Problem: out = u2 + trilinear(u1, grid + u2); B=2, D=H=W=160, C=3, fp32.
constexpr int Bn = 2;
constexpr int Dn = 160;
constexpr int Hn = 160;
constexpr int Wn = 160;
constexpr int NV = Bn * Dn * Hn * Wn;          // 8,192,000 voxels
constexpr int VOL = Dn * Hn * Wn;              // 4,096,000 voxels / batch

__global__ __launch_bounds__(256) void compose_transform_kernel(
    const float* __restrict__ warp1,
    const float* __restrict__ warp2,
    float* __restrict__ out) {
    int idx = blockIdx.x * blockDim.x + threadIdx.x;   // voxel id over B*D*H*W
    if (idx >= NV) return;

    // decode (b, d, h, w)
    int w  = idx % Wn;
    int t  = idx / Wn;
    int h  = t % Hn;
    t      = t / Hn;
    int d  = t % Dn;
    int b  = t / Dn;

    int base3 = idx * 3;
    // streaming read — nontemporal to keep L2 for the warp1 gathers
    float u2x = __builtin_nontemporal_load(warp2 + base3 + 0);
    float u2y = __builtin_nontemporal_load(warp2 + base3 + 1);
    float u2z = __builtin_nontemporal_load(warp2 + base3 + 2);

    // loc = grid + u2, clipped to [0, size-1]
    float lx = fminf(fmaxf((float)d + u2x, 0.0f), (float)(Dn - 1));
    float ly = fminf(fmaxf((float)h + u2y, 0.0f), (float)(Hn - 1));
    float lz = fminf(fmaxf((float)w + u2z, 0.0f), (float)(Wn - 1));

    // Border-remapped bases: ixb in [0, size-2]; weight on ixb is 0 when
    // the reference would have clamped (lx == size-1), matching i1=min(i0+1,..)
    // semantics exactly (the clamped duplicate corner gets full weight).
    int ixb = min((int)floorf(lx), Dn - 2);
    int iyb = min((int)floorf(ly), Hn - 2);
    int izb = min((int)floorf(lz), Wn - 2);

    float wx1 = lx - (float)ixb, wx0 = 1.0f - wx1;
    float wy1 = ly - (float)iyb, wy0 = 1.0f - wy1;
    float wz1 = lz - (float)izb, wz0 = 1.0f - wz1;

    const float* __restrict__ u1 = warp1 + b * (VOL * 3);

    // 4 (x,y) rows; each row reads voxels (izb, izb+1) = 6 contiguous floats.
    const float* p00 = u1 + ((ixb       * Hn + iyb    ) * Wn + izb) * 3;
    const float* p01 = u1 + ((ixb       * Hn + iyb + 1) * Wn + izb) * 3;
    const float* p10 = u1 + (((ixb + 1) * Hn + iyb    ) * Wn + izb) * 3;
    const float* p11 = u1 + (((ixb + 1) * Hn + iyb + 1) * Wn + izb) * 3;

    // Issue all gather loads before any use — maximize loads in flight.
    float a00_0 = p00[0], a00_1 = p00[1], a00_2 = p00[2];
    float a00_3 = p00[3], a00_4 = p00[4], a00_5 = p00[5];
    float a01_0 = p01[0], a01_1 = p01[1], a01_2 = p01[2];
    float a01_3 = p01[3], a01_4 = p01[4], a01_5 = p01[5];
    float a10_0 = p10[0], a10_1 = p10[1], a10_2 = p10[2];
    float a10_3 = p10[3], a10_4 = p10[4], a10_5 = p10[5];
    float a11_0 = p11[0], a11_1 = p11[1], a11_2 = p11[2];
    float a11_3 = p11[3], a11_4 = p11[4], a11_5 = p11[5];

    float w00 = wx0 * wy0;
    float w01 = wx0 * wy1;
    float w10 = wx1 * wy0;
    float w11 = wx1 * wy1;

    // Per row: wz0 * c[z0] + wz1 * c[z1], then weighted by wxy.
    float rx, ry, rz;
    float accx, accy, accz;

    rx = fmaf(wz1, a00_3, wz0 * a00_0);
    ry = fmaf(wz1, a00_4, wz0 * a00_1);
    rz = fmaf(wz1, a00_5, wz0 * a00_2);
    accx = w00 * rx; accy = w00 * ry; accz = w00 * rz;

    rx = fmaf(wz1, a01_3, wz0 * a01_0);
    ry = fmaf(wz1, a01_4, wz0 * a01_1);
    rz = fmaf(wz1, a01_5, wz0 * a01_2);
    accx = fmaf(w01, rx, accx); accy = fmaf(w01, ry, accy); accz = fmaf(w01, rz, accz);

    rx = fmaf(wz1, a10_3, wz0 * a10_0);
    ry = fmaf(wz1, a10_4, wz0 * a10_1);
    rz = fmaf(wz1, a10_5, wz0 * a10_2);
    accx = fmaf(w10, rx, accx); accy = fmaf(w10, ry, accy); accz = fmaf(w10, rz, accz);

    rx = fmaf(wz1, a11_3, wz0 * a11_0);
    ry = fmaf(wz1, a11_4, wz0 * a11_1);
    rz = fmaf(wz1, a11_5, wz0 * a11_2);
    accx = fmaf(w11, rx, accx); accy = fmaf(w11, ry, accy); accz = fmaf(w11, rz, accz);

    // streaming write — nontemporal
    __builtin_nontemporal_store(u2x + accx, out + base3 + 0);
    __builtin_nontemporal_store(u2y + accy, out + base3 + 1);
    __builtin_nontemporal_store(u2z + accz, out + base3 + 2);
}

extern "C" void kernel_launch(void* const* d_in, const int* in_sizes, int n_in,
                              void* d_out, int out_size, void* d_ws, size_t ws_size,
                              hipStream_t stream) {
    const float* warp1 = (const float*)d_in[0];
    const float* warp2 = (const float*)d_in[1];
    float* out = (float*)d_out;

    int threads = 256;
    int blocks = (NV + threads - 1) / threads;   // 32000 blocks
    compose_transform_kernel<<<blocks, threads, 0, stream>>>(warp1, warp2, out);
}